// Round 8
// baseline (320.906 us; speedup 1.0000x reference)
//
#include <hip/hip_runtime.h>

typedef float f32x4 __attribute__((ext_vector_type(4)));
typedef float fvec4 __attribute__((ext_vector_type(4)));
typedef __bf16 bf16x8 __attribute__((ext_vector_type(8)));
typedef unsigned short u16;
typedef u16 u16x8 __attribute__((ext_vector_type(8)));
typedef u16 u16x4 __attribute__((ext_vector_type(4)));
typedef int i32x2 __attribute__((ext_vector_type(2)));

#define SCALE_Q 0.18257418583505536f   /* 30^-0.5 */
#define LOG2E   1.4426950408889634f
#define SCALE_Q2 (SCALE_Q * LOG2E)     /* folded: exp(s) = 2^(s*log2e) */

__device__ __forceinline__ u16 f2bf(float f) {
    union { __bf16 h; u16 u; } cv; cv.h = (__bf16)f; return cv.u;
}
__device__ __forceinline__ float bf2f(u16 u) {
    union { __bf16 h; u16 u; } cv; cv.u = u; return (float)cv.h;
}
__device__ __forceinline__ float exp2_raw(float x) {
    float r;
    asm("v_exp_f32 %0, %1" : "=v"(r) : "v"(x));
    return r;
}

// async global->LDS, 16B per lane; LDS dest = wave-uniform base + lane*16
#define GLD16(gsrc, ldst) __builtin_amdgcn_global_load_lds( \
    (const __attribute__((address_space(1))) unsigned*)(gsrc), \
    (__attribute__((address_space(3))) unsigned*)(ldst), 16, 0, 0)

// lane^16 cross-exchange pair: u[l]=(l&16)?b[l^16]:a[l]; v[l]=(l&16)?b[l]:a[l^16]
__device__ __forceinline__ void xswap16(int a, int b, int& u, int& v) {
#if __has_builtin(__builtin_amdgcn_permlane16_swap)
    i32x2 r = __builtin_amdgcn_permlane16_swap(a, b, false, false);
    u = r[0]; v = r[1];
#else
    int sa = __builtin_amdgcn_ds_swizzle(a, 0x401F);
    int sb = __builtin_amdgcn_ds_swizzle(b, 0x401F);
    bool hi = (threadIdx.x & 16) != 0;
    u = hi ? sb : a;
    v = hi ? b : sa;
#endif
}

// ---------------------------------------------------------------------------
// prep: weight transposes, bias table (*log2e), K_pad fills, vP plane/border
// ---------------------------------------------------------------------------
__device__ __forceinline__ void border_yx(int i, int& y, int& x) {
    if (i < 1056)      { y = i / 264; x = i % 264; }
    else if (i < 2112) { int j = i - 1056; y = 260 + j / 264; x = j % 264; }
    else               { int j = i - 2112; y = 4 + (j >> 3); int xx = j & 7;
                         x = (xx < 4) ? xx : 256 + xx; }
}

__global__ __launch_bounds__(256)
void prep_k(const float* __restrict__ qkv_w, const float* __restrict__ proj_w,
            const float* __restrict__ fc1_w, const float* __restrict__ fc2_w,
            const int* __restrict__ rpi, const float* __restrict__ rpb,
            u16* __restrict__ qkvT, u16* __restrict__ projT,
            u16* __restrict__ fc1T, u16* __restrict__ fc2T,
            u16* __restrict__ bias5, unsigned* __restrict__ kp_u32,
            unsigned* __restrict__ vp_u32)
{
    int idx = blockIdx.x * 256 + threadIdx.x;
    if (idx < 122880) {                        // qkvT[640][192]
        int col = idx / 192, k = idx % 192;
        qkvT[idx] = (col < 540 && k < 180) ? f2bf(qkv_w[k * 540 + col]) : (u16)0;
    } else if (idx < 172032) {                 // projT[256][192]
        int i = idx - 122880; int col = i / 192, k = i % 192;
        projT[i] = (col < 180 && k < 180) ? f2bf(proj_w[k * 180 + col]) : (u16)0;
    } else if (idx < 245760) {                 // fc1T[384][192]
        int i = idx - 172032; int col = i / 192, k = i % 192;
        fc1T[i] = (col < 360 && k < 180) ? f2bf(fc1_w[k * 360 + col]) : (u16)0;
    } else if (idx < 344064) {                 // fc2T[256][384]
        int i = idx - 245760; int col = i / 384, k = i % 384;
        fc2T[i] = (col < 180 && k < 360) ? f2bf(fc2_w[k * 180 + col]) : (u16)0;
    } else if (idx < 1228800) {                // bias5[(h*36+ch*4+mi)][lg][wv][l15][e]
        int i = idx - 344064;
        int e = i & 15, l15 = (i >> 4) & 15, wv2 = (i >> 8) & 3, lg2 = (i >> 10) & 3;
        int cm36 = i >> 12;
        int hh = cm36 / 36, cm = cm36 % 36;
        int ch = cm >> 2, mi = cm & 3;
        int ni = e >> 2, rr = e & 3;
        int q = wv2 * 64 + ni * 16 + l15;
        int key = ch * 64 + mi * 16 + lg2 * 4 + rr;
        bias5[i] = f2bf(rpb[rpi[q * 576 + key] * 6 + hh] * LOG2E);
    } else if (idx < 1628160) {                // K_pad border tokens (u32 x16)
        int i = idx - 1228800;
        int tok = i >> 4, wj = i & 15;
        int h = tok / 4160, b = tok % 4160, y, x;
        border_yx(b, y, x);
        kp_u32[((h * 264 + y) * 264 + x) * 16 + wj] = 0u;
    } else if (idx < 2021376) {                // K_pad interior dims 30,31
        int i = idx - 1628160;
        int h = i / 65536, t = i % 65536;
        int y = t >> 8, x = t & 255;
        kp_u32[((h * 264 + y + 4) * 264 + x + 4) * 16 + 15] = 0u;
    } else if (idx < 2236800) {                // vP d=30 plane := 1.0
        int i = idx - 2021376;                 // plane = 264*136 u32 = 35904
        int h = i / 35904, r = i % 35904;
        vp_u32[(h * 32 + 30) * 35904 + r] = 0x3F803F80u;
    } else if (idx < 2452224) {                // vP d=31 plane := 0
        int i = idx - 2236800;
        int h = i / 35904, r = i % 35904;
        vp_u32[(h * 32 + 31) * 35904 + r] = 0u;
    } else if (idx < 3016704) {                // vP d<30 borders := 0
        int i = idx - 2452224;                 // 3136 u32 per (h,d)
        int hd = i / 3136, j = i % 3136;
        int h = hd / 30, d = hd % 30;
        int y, xu;
        if (j < 1088) { int r = j / 136; y = r + (r >= 4 ? 256 : 0); xu = j % 136; }
        else { int j2 = j - 1088; y = 4 + (j2 >> 3); int q = j2 & 7;
               xu = (q < 2) ? q : 128 + q; }
        vp_u32[((h * 32 + d) * 264 + y) * 136 + xu] = 0u;
    }
}

// ---------------------------------------------------------------------------
// LayerNorm: wave per row (180 f32 = 45 float4), writes bf16 [row][192]
// ---------------------------------------------------------------------------
__global__ __launch_bounds__(256)
void ln_k(const float* __restrict__ in, const float* __restrict__ w,
          const float* __restrict__ b, u16* __restrict__ out)
{
    int row = blockIdx.x * 4 + (threadIdx.x >> 6);
    int lane = threadIdx.x & 63;
    fvec4 v = {0.f, 0.f, 0.f, 0.f};
    if (lane < 45) v = *(const fvec4*)(in + (long)row * 180 + lane * 4);
    float s  = v.x + v.y + v.z + v.w;
    float sq = v.x * v.x + v.y * v.y + v.z * v.z + v.w * v.w;
    for (int m = 1; m < 64; m <<= 1) { s += __shfl_xor(s, m); sq += __shfl_xor(sq, m); }
    float mean = s * (1.f / 180.f);
    float var  = sq * (1.f / 180.f) - mean * mean;
    float rstd = rsqrtf(var + 1e-5f);
    if (lane < 45) {
        u16x4 o;
        #pragma unroll
        for (int j = 0; j < 4; j++) {
            int c = lane * 4 + j;
            o[j] = f2bf((v[j] - mean) * rstd * w[c] + b[c]);
        }
        *(u16x4*)(out + (long)row * 192 + lane * 4) = o;
    } else if (lane < 48) {
        u16x4 z = {0, 0, 0, 0};
        *(u16x4*)(out + (long)row * 192 + 180 + (lane - 45) * 4) = z;
    }
}

// ---------------------------------------------------------------------------
// V transpose -> planar vP[h][32][264][272] (x shifted +4 so every 8-key row
// slice is 16B-aligned). Interior d<30 written here; borders/d30=1.0/d31=0
// pre-filled by prep. Block per (image row y, head).
// ---------------------------------------------------------------------------
__global__ __launch_bounds__(256)
void vtr_k(const u16* __restrict__ v_s, u16* __restrict__ vP)
{
    __shared__ u16 tile[32][268];
    const int y = blockIdx.x, h = blockIdx.y;
    const int t = threadIdx.x;
    #pragma unroll
    for (int k2 = 0; k2 < 4; ++k2) {
        int u = t + k2 * 256;                 // 1024 units: x = u>>2, dp=(u&3)*8
        int x = u >> 2, dp = (u & 3) * 8;
        u16x8 v = *(const u16x8*)(v_s + (((long)(y * 256 + x)) * 6 + h) * 32 + dp);
        #pragma unroll
        for (int j = 0; j < 8; j++) tile[dp + j][x] = v[j];
    }
    __syncthreads();
    const long base = (((long)h * 32) * 264 + y + 4) * 272 + 4;
    #pragma unroll
    for (int k2 = 0; k2 < 4; ++k2) {
        int u = t + k2 * 256;
        if (u < 960) {                        // 30 d-rows x 32 x-groups
            int d = u >> 5, xg = u & 31;
            u16x4 a = *(const u16x4*)(&tile[d][xg * 8]);
            u16x4 b = *(const u16x4*)(&tile[d][xg * 8 + 4]);
            long dst = base + (long)d * (264 * 272) + xg * 8;
            *(u16x4*)(vP + dst) = a;
            *(u16x4*)(vP + dst + 4) = b;
        }
    }
}

// ---------------------------------------------------------------------------
// GEMM: C[M][N] = A[M][K]bf16 @ Bt[N][K]bf16, 128x64 tile, 4 waves 2x2.
// B panel hoisted to REGISTERS (whole K for 192; per-192-half for 384) — it
// is L1/L2-hot across all row-blocks. A double-buffered in LDS (16KB), ONE
// barrier per K-step: stage(k+1) issued right after the barrier, drained at
// the NEXT barrier -> full compute phase of latency cover.
// ---------------------------------------------------------------------------
template<int KTOT, int EPI>
__global__ __launch_bounds__(256)
void gemm_k(const u16* __restrict__ A, const u16* __restrict__ Bt,
            const float* __restrict__ bias, const float* __restrict__ resid,
            void* __restrict__ o0, void* __restrict__ o1, void* __restrict__ o2)
{
    constexpr int NK = KTOT / 32;
    constexpr int GK = (NK > 6) ? 6 : NK;      // B-reg group (48 VGPR)
    __shared__ u16 lds_a[2][128 * 32];
    const int tid = threadIdx.x;
    const int l = tid & 63, wv = tid >> 6;
    const int wm = wv >> 1, wn = wv & 1;
    const int l15 = l & 15, lg = l >> 4;
    const int swz = (lg ^ ((l15 >> 1) & 3)) * 8;
    const long rowb = (long)blockIdx.x * 128;
    const int colb = blockIdx.y * 64;
    const f32x4 fz = {0.f, 0.f, 0.f, 0.f};

    f32x4 acc[4][2];
    #pragma unroll
    for (int i = 0; i < 4; i++) { acc[i][0] = fz; acc[i][1] = fz; }

    const int r = tid >> 2, g = tid & 3;
    const int gsw = (g ^ ((r >> 1) & 3)) * 8;
    const u16* Ar0 = A + (rowb + r) * KTOT + gsw;
    const u16* Ar1 = A + (rowb + 64 + r) * KTOT + gsw;
    const u16* Bb  = Bt + (long)(colb + wn * 32 + l15) * KTOT + lg * 8;

    // stage(0)
    GLD16(Ar0, (char*)lds_a[0] + wv * 1024);
    GLD16(Ar1, (char*)lds_a[0] + 4096 + wv * 1024);

    for (int kg = 0; kg < NK; kg += GK) {
        bf16x8 bfr[2][GK];
        #pragma unroll
        for (int g2 = 0; g2 < GK; ++g2) {
            bfr[0][g2] = *(const bf16x8*)(Bb + (kg + g2) * 32);
            bfr[1][g2] = *(const bf16x8*)(Bb + 16 * KTOT + (kg + g2) * 32);
        }
        #pragma unroll
        for (int g2 = 0; g2 < GK; ++g2) {
            const int k = kg + g2;
            __syncthreads();                  // buf k ready; buf (k+1)&1 free
            if (k + 1 < NK) {
                GLD16(Ar0 + (k + 1) * 32, (char*)lds_a[(k + 1) & 1] + wv * 1024);
                GLD16(Ar1 + (k + 1) * 32, (char*)lds_a[(k + 1) & 1] + 4096 + wv * 1024);
            }
            const u16* la = lds_a[k & 1];
            bf16x8 af[4];
            #pragma unroll
            for (int mi = 0; mi < 4; mi++)
                af[mi] = *(const bf16x8*)(la + (wm * 64 + mi * 16 + l15) * 32 + swz);
            #pragma unroll
            for (int mi = 0; mi < 4; mi++)
                #pragma unroll
                for (int nd = 0; nd < 2; nd++)
                    acc[mi][nd] = __builtin_amdgcn_mfma_f32_16x16x32_bf16(af[mi], bfr[nd][g2], acc[mi][nd], 0, 0, 0);
        }
    }

    #pragma unroll
    for (int mi = 0; mi < 4; mi++) {
        #pragma unroll
        for (int nd = 0; nd < 2; nd++) {
            #pragma unroll
            for (int rr = 0; rr < 4; rr++) {
                long t = rowb + wm * 64 + mi * 16 + lg * 4 + rr;
                int c = colb + wn * 32 + nd * 16 + l15;
                float v = acc[mi][nd][rr];
                if (EPI == 0) {
                    if (c < 540) {
                        v += bias[c];
                        int y = (int)(t >> 8), x = (int)(t & 255);
                        if (c < 180) {
                            int hh = c / 30, d = c % 30;
                            int win = ((y >> 4) << 4) | (x >> 4);
                            int qrow = ((y & 15) << 4) | (x & 15);
                            ((u16*)o0)[(((long)(win * 6 + hh)) * 256 + qrow) * 32 + d] = f2bf(v * SCALE_Q2);
                        } else if (c < 360) {
                            int c2 = c - 180; int hh = c2 / 30, d = c2 % 30;
                            ((u16*)o1)[(((long)hh * 264 + y + 4) * 264 + x + 4) * 32 + d] = f2bf(v);
                        } else {
                            int c2 = c - 360; int hh = c2 / 30, d = c2 % 30;
                            ((u16*)o2)[(t * 6 + hh) * 32 + d] = f2bf(v);
                        }
                    }
                } else if (EPI == 1) {
                    if (c < 180) ((float*)o0)[t * 180 + c] = v + bias[c] + resid[t * 180 + c];
                } else if (EPI == 2) {
                    float bb = (c < 360) ? bias[c] : 0.f;
                    float xx = v + bb;
                    float u2n = -2.f * xx * (0.7978845608f + 0.0356774081f * xx * xx);
                    float ge = xx / (1.f + __expf(u2n));
                    ((u16*)o0)[t * 384 + c] = f2bf(ge);
                } else {
                    if (c < 180) ((float*)o0)[t * 180 + c] = v + bias[c] + resid[t * 180 + c];
                }
            }
        }
    }
}

// ---------------------------------------------------------------------------
// Attention: block=(window,head), 4 waves x 64 q, 9 chunks of 64 keys.
// K staged via GLD16 from K_pad; V via 1 GLD16/wave from planar vP (16B-
// aligned 8-key row slices). Swapped QK^T; P redistributed in-register.
// Softmax denom via vP d=30 == 1.0. Bias (pre-scaled log2e) as MFMA C-input;
// Q pre-scaled SCALE*log2e -> P = v_exp_f32(S) direct.
// ---------------------------------------------------------------------------
__global__ __launch_bounds__(256)
void attn_k(const u16* __restrict__ q_g, const u16* __restrict__ K_pad,
            const u16* __restrict__ vP, const u16* __restrict__ bias5,
            u16* __restrict__ attn_out)
{
    __shared__ u16 kc[2][64 * 32];
    __shared__ u16 vt[2][32 * 64];

    const int w = ((blockIdx.x & 7) << 5) | (blockIdx.x >> 3);   // XCD swizzle
    const int h = blockIdx.y;
    const int wy = w >> 4, wx = w & 15;
    const int tid = threadIdx.x;
    const int wv = tid >> 6, l = tid & 63;
    const int l15 = l & 15, lg = l >> 4;
    const int swzk = (l15 >> 1) & 3;
    const int swzv = l15 & 7;

    bf16x8 qb[4];
    #pragma unroll
    for (int ni = 0; ni < 4; ni++) {
        int qrow = wv * 64 + ni * 16 + l15;
        qb[ni] = *(const bf16x8*)(q_g + (((long)(w * 6 + h)) * 256 + qrow) * 32 + lg * 8);
    }

    f32x4 acc[2][4];
    #pragma unroll
    for (int i = 0; i < 2; i++)
        #pragma unroll
        for (int j = 0; j < 4; j++) acc[i][j] = (f32x4){0.f, 0.f, 0.f, 0.f};

    // K staging: token tK = tid>>2, dim-group gtk (inverse-swizzled)
    const int tK = tid >> 2;
    const int gtk = (l & 3) ^ ((l >> 3) & 3);
    const int aK = (tK >= 48) ? 2 : (tK >= 24 ? 1 : 0);
    const int bK = tK - aK * 24;
    const u16* KbaseRow = K_pad + (((long)(h * 264 + wy * 16)) * 264 + wx * 16) * 32 + gtk * 8;
    // V staging from planar vP: dim dV = tid>>3, key-group gtv (inv-swizzled)
    const int dV = tid >> 3;
    const int gtv = (l & 7) ^ (l >> 3);
    const int aV = gtv / 3, bV = (gtv % 3) * 8;
    const u16* Vrow0 = vP + ((((long)h * 32 + dV) * 264) + wy * 16) * 272 + wx * 16;
    // bias base (fragment layout)
    const u16* Bp = bias5 + (long)h * 147456 + ((lg * 4 + wv) * 16 + l15) * 16;

    GLD16(KbaseRow + ((long)aK * 264 + bK) * 32, (char*)kc[0] + wv * 1024);
    GLD16(Vrow0 + aV * 272 + bV, (char*)vt[0] + wv * 1024);

    #pragma unroll
    for (int ch = 0; ch < 9; ++ch) {
        __syncthreads();
        u16x8 bl[4], bh[4];
        #pragma unroll
        for (int mi = 0; mi < 4; mi++) {
            bl[mi] = *(const u16x8*)(Bp + (ch * 4 + mi) * 4096);
            bh[mi] = *(const u16x8*)(Bp + (ch * 4 + mi) * 4096 + 8);
        }
        if (ch < 8) {
            int n = (ch + 1) * 64;
            int c1 = n / 24, c2 = n - c1 * 24;
            int bb2 = bK + c2;
            int t2 = bb2 >= 24;
            int oy = c1 + aK + t2, ox = bb2 - (t2 ? 24 : 0);
            GLD16(KbaseRow + ((long)oy * 264 + ox) * 32, (char*)kc[(ch + 1) & 1] + wv * 1024);
            int bbv = bV + c2;
            int t2v = bbv >= 24;
            int oyv = c1 + aV + t2v, oxv = bbv - (t2v ? 24 : 0);
            GLD16(Vrow0 + oyv * 272 + oxv, (char*)vt[(ch + 1) & 1] + wv * 1024);
        }
        const u16* kcur = kc[ch & 1];
        const u16* vcur = vt[ch & 1];

        #pragma unroll
        for (int ks = 0; ks < 2; ++ks) {
            int Wp[2][4][2];
            #pragma unroll
            for (int mih = 0; mih < 2; ++mih) {
                int mi = ks * 2 + mih;
                int key = ks * 32 + mih * 16 + l15;
                bf16x8 ka = *(const bf16x8*)(kcur + key * 32 + (lg ^ swzk) * 8);
                union { u16x8 v; unsigned d[4]; } ulo, uhi;
                ulo.v = bl[mi]; uhi.v = bh[mi];
                f32x4 s[4];
                #pragma unroll
                for (int ni = 0; ni < 4; ni++) {
                    unsigned dA = (ni < 2) ? ulo.d[(ni & 1) * 2]     : uhi.d[(ni & 1) * 2];
                    unsigned dB = (ni < 2) ? ulo.d[(ni & 1) * 2 + 1] : uhi.d[(ni & 1) * 2 + 1];
                    f32x4 ci;
                    ci[0] = __uint_as_float(dA << 16);
                    ci[1] = __uint_as_float(dA & 0xFFFF0000u);
                    ci[2] = __uint_as_float(dB << 16);
                    ci[3] = __uint_as_float(dB & 0xFFFF0000u);
                    s[ni] = ci;
                }
                #pragma unroll
                for (int ni = 0; ni < 4; ni++)
                    s[ni] = __builtin_amdgcn_mfma_f32_16x16x32_bf16(ka, qb[ni], s[ni], 0, 0, 0);
                #pragma unroll
                for (int ni = 0; ni < 4; ni++) {
                    float p0 = exp2_raw(s[ni][0]);
                    float p1 = exp2_raw(s[ni][1]);
                    float p2 = exp2_raw(s[ni][2]);
                    float p3 = exp2_raw(s[ni][3]);
                    int wlo, whi;
                    asm("v_cvt_pk_bf16_f32 %0, %1, %2" : "=v"(wlo) : "v"(p0), "v"(p1));
                    asm("v_cvt_pk_bf16_f32 %0, %1, %2" : "=v"(whi) : "v"(p2), "v"(p3));
                    Wp[mih][ni][0] = wlo;
                    Wp[mih][ni][1] = whi;
                }
            }
            bf16x8 va0 = *(const bf16x8*)(vcur + l15 * 64 + ((ks * 4 + lg) ^ swzv) * 8);
            bf16x8 va1 = *(const bf16x8*)(vcur + (16 + l15) * 64 + ((ks * 4 + lg) ^ swzv) * 8);
            #pragma unroll
            for (int ni = 0; ni < 4; ni++) {
                i32x2 r0 = __builtin_amdgcn_permlane32_swap(Wp[0][ni][0], Wp[1][ni][0], false, false);
                i32x2 r1 = __builtin_amdgcn_permlane32_swap(Wp[0][ni][1], Wp[1][ni][1], false, false);
                int wd0, wd1, wd2, wd3;
                xswap16(r0[0], r0[1], wd0, wd2);
                xswap16(r1[0], r1[1], wd1, wd3);
                union { int wd[4]; bf16x8 v; } pu;
                pu.wd[0] = wd0; pu.wd[1] = wd1; pu.wd[2] = wd2; pu.wd[3] = wd3;
                acc[0][ni] = __builtin_amdgcn_mfma_f32_16x16x32_bf16(va0, pu.v, acc[0][ni], 0, 0, 0);
                acc[1][ni] = __builtin_amdgcn_mfma_f32_16x16x32_bf16(va1, pu.v, acc[1][ni], 0, 0, 0);
            }
        }
    }

    // epilogue: O^T row d=30 holds sum(P); divide, scatter dims<30
    #pragma unroll
    for (int ni = 0; ni < 4; ni++) {
        float sum = __shfl(acc[1][ni][2], 48 + l15);
        float inv = 1.f / sum;
        int q = wv * 64 + ni * 16 + l15;
        int y = wy * 16 + (q >> 4), x = wx * 16 + (q & 15);
        long base = ((long)(y * 256 + x)) * 192 + h * 30;
        #pragma unroll
        for (int mi2 = 0; mi2 < 2; mi2++)
            #pragma unroll
            for (int rr = 0; rr < 4; rr++) {
                int dim = mi2 * 16 + lg * 4 + rr;
                if (dim < 30)
                    attn_out[base + dim] = f2bf(acc[mi2][ni][rr] * inv);
            }
    }
}

// ---------------------------------------------------------------------------
extern "C" void kernel_launch(void* const* d_in, const int* in_sizes, int n_in,
                              void* d_out, int out_size, void* d_ws, size_t ws_size,
                              hipStream_t stream)
{
    (void)in_sizes; (void)n_in; (void)out_size; (void)ws_size;
    const float* x      = (const float*)d_in[0];
    const int*   rpi    = (const int*)d_in[1];
    const float* n1w    = (const float*)d_in[2];
    const float* n1b    = (const float*)d_in[3];
    const float* qkv_w  = (const float*)d_in[4];
    const float* qkv_b  = (const float*)d_in[5];
    const float* rpb    = (const float*)d_in[6];
    const float* proj_w = (const float*)d_in[7];
    const float* proj_b = (const float*)d_in[8];
    const float* n2w    = (const float*)d_in[9];
    const float* n2b    = (const float*)d_in[10];
    const float* fc1_w  = (const float*)d_in[11];
    const float* fc1_b  = (const float*)d_in[12];
    const float* fc2_w  = (const float*)d_in[13];
    const float* fc2_b  = (const float*)d_in[14];
    float* out = (float*)d_out;

    char* ws = (char*)d_ws;
    size_t off = 0;
    auto alloc = [&](size_t bytes) -> void* {
        void* p = ws + off; off += (bytes + 511) & ~(size_t)511; return p;
    };
    u16*   xn     = (u16*)alloc(65536ull * 192 * 2);        // ln out; ao aliases
    u16*   q_g    = (u16*)alloc(65536ull * 192 * 2);        // [win][h][q][32]
    u16*   K_pad  = (u16*)alloc(6ull * 264 * 264 * 32 * 2); // [h][y][x][32]
    u16*   v_s    = (u16*)alloc(65536ull * 180 * 4);        // aliased with x2
    float* x2     = (float*)v_s;                            // v_s dead before proj
    u16*   vP     = (u16*)alloc(6ull * 32 * 264 * 272 * 2); // [h][d][y+4][x+4]
    u16*   bias5  = (u16*)alloc(6ull * 36 * 4 * 4 * 16 * 16 * 2);
    u16*   qkvT   = (u16*)alloc(640ull * 192 * 2);
    u16*   projT  = (u16*)alloc(256ull * 192 * 2);
    u16*   fc1T   = (u16*)alloc(384ull * 192 * 2);
    u16*   fc2T   = (u16*)alloc(256ull * 384 * 2);
    u16*   ao     = xn;    // ln_k zero-fills cols 180..191; attn fills 0..179
    u16*   h1     = q_g;   // fc1 out [t][384]: q_g+K_pad adjacent >= 50.3MB

    prep_k<<<dim3(11784), dim3(256), 0, stream>>>(qkv_w, proj_w, fc1_w, fc2_w,
        rpi, rpb, qkvT, projT, fc1T, fc2T, bias5, (unsigned*)K_pad, (unsigned*)vP);
    ln_k<<<dim3(16384), dim3(256), 0, stream>>>(x, n1w, n1b, xn);
    gemm_k<192, 0><<<dim3(512, 9), dim3(256), 0, stream>>>(
        xn, qkvT, qkv_b, (const float*)nullptr, q_g, K_pad, v_s);
    vtr_k<<<dim3(256, 6), dim3(256), 0, stream>>>(v_s, vP);
    attn_k<<<dim3(256, 6), dim3(256), 0, stream>>>(q_g, K_pad, vP, bias5, ao);
    gemm_k<192, 1><<<dim3(512, 3), dim3(256), 0, stream>>>(
        ao, projT, proj_b, x, x2, nullptr, nullptr);
    ln_k<<<dim3(16384), dim3(256), 0, stream>>>(x2, n2w, n2b, xn);
    gemm_k<192, 2><<<dim3(512, 6), dim3(256), 0, stream>>>(
        xn, fc1T, fc1_b, (const float*)nullptr, h1, nullptr, nullptr);
    gemm_k<384, 3><<<dim3(512, 3), dim3(256), 0, stream>>>(
        h1, fc2T, fc2_b, x2, out, nullptr, nullptr);
}

// Round 9
// 287.884 us; speedup vs baseline: 1.1147x; 1.1147x over previous
//
#include <hip/hip_runtime.h>

typedef float f32x4 __attribute__((ext_vector_type(4)));
typedef float fvec4 __attribute__((ext_vector_type(4)));
typedef __bf16 bf16x8 __attribute__((ext_vector_type(8)));
typedef unsigned short u16;
typedef u16 u16x8 __attribute__((ext_vector_type(8)));
typedef u16 u16x4 __attribute__((ext_vector_type(4)));
typedef int i32x2 __attribute__((ext_vector_type(2)));

#define SCALE_Q 0.18257418583505536f   /* 30^-0.5 */
#define LOG2E   1.4426950408889634f
#define SCALE_Q2 (SCALE_Q * LOG2E)     /* folded: exp(s) = 2^(s*log2e) */

__device__ __forceinline__ u16 f2bf(float f) {
    union { __bf16 h; u16 u; } cv; cv.h = (__bf16)f; return cv.u;
}
__device__ __forceinline__ float bf2f(u16 u) {
    union { __bf16 h; u16 u; } cv; cv.u = u; return (float)cv.h;
}
__device__ __forceinline__ float exp2_raw(float x) {
    float r;
    asm("v_exp_f32 %0, %1" : "=v"(r) : "v"(x));
    return r;
}
__device__ __forceinline__ unsigned pk_bf16(float a, float b) {
    unsigned r;
    asm("v_cvt_pk_bf16_f32 %0, %1, %2" : "=v"(r) : "v"(a), "v"(b));
    return r;
}

// async global->LDS, 16B per lane; LDS dest = wave-uniform base + lane*16
#define GLD16(gsrc, ldst) __builtin_amdgcn_global_load_lds( \
    (const __attribute__((address_space(1))) unsigned*)(gsrc), \
    (__attribute__((address_space(3))) unsigned*)(ldst), 16, 0, 0)

// lane^16 cross-exchange pair
__device__ __forceinline__ void xswap16(int a, int b, int& u, int& v) {
#if __has_builtin(__builtin_amdgcn_permlane16_swap)
    i32x2 r = __builtin_amdgcn_permlane16_swap(a, b, false, false);
    u = r[0]; v = r[1];
#else
    int sa = __builtin_amdgcn_ds_swizzle(a, 0x401F);
    int sb = __builtin_amdgcn_ds_swizzle(b, 0x401F);
    bool hi = (threadIdx.x & 16) != 0;
    u = hi ? sb : a;
    v = hi ? b : sa;
#endif
}

// ---------------------------------------------------------------------------
// prep + ln1 merged: blocks [0,16384) do LayerNorm(x) -> xn bf16 [row][192];
// blocks [16384, 28168) do weight transposes, bias table, K_pad/vP fills.
// ---------------------------------------------------------------------------
__device__ __forceinline__ void border_yx(int i, int& y, int& x) {
    if (i < 1056)      { y = i / 264; x = i % 264; }
    else if (i < 2112) { int j = i - 1056; y = 260 + j / 264; x = j % 264; }
    else               { int j = i - 2112; y = 4 + (j >> 3); int xx = j & 7;
                         x = (xx < 4) ? xx : 256 + xx; }
}

__global__ __launch_bounds__(256)
void prepln_k(const float* __restrict__ x, const float* __restrict__ n1w,
              const float* __restrict__ n1b, u16* __restrict__ xn,
              const float* __restrict__ qkv_w, const float* __restrict__ proj_w,
              const float* __restrict__ fc1_w, const float* __restrict__ fc2_w,
              const int* __restrict__ rpi, const float* __restrict__ rpb,
              u16* __restrict__ qkvT, u16* __restrict__ projT,
              u16* __restrict__ fc1T, u16* __restrict__ fc2T,
              u16* __restrict__ bias5, unsigned* __restrict__ kp_u32,
              unsigned* __restrict__ vp_u32)
{
    if (blockIdx.x < 16384) {      // ----- LayerNorm1 -----
        int row = blockIdx.x * 4 + (threadIdx.x >> 6);
        int lane = threadIdx.x & 63;
        fvec4 v = {0.f, 0.f, 0.f, 0.f};
        if (lane < 45) v = *(const fvec4*)(x + (long)row * 180 + lane * 4);
        float s  = v.x + v.y + v.z + v.w;
        float sq = v.x * v.x + v.y * v.y + v.z * v.z + v.w * v.w;
        for (int m = 1; m < 64; m <<= 1) { s += __shfl_xor(s, m); sq += __shfl_xor(sq, m); }
        float mean = s * (1.f / 180.f);
        float var  = sq * (1.f / 180.f) - mean * mean;
        float rstd = rsqrtf(var + 1e-5f);
        if (lane < 45) {
            u16x4 o;
            #pragma unroll
            for (int j = 0; j < 4; j++) {
                int c = lane * 4 + j;
                o[j] = f2bf((v[j] - mean) * rstd * n1w[c] + n1b[c]);
            }
            *(u16x4*)(xn + (long)row * 192 + lane * 4) = o;
        } else if (lane < 48) {
            u16x4 z = {0, 0, 0, 0};
            *(u16x4*)(xn + (long)row * 192 + 180 + (lane - 45) * 4) = z;
        }
        return;
    }
    int idx = (blockIdx.x - 16384) * 256 + threadIdx.x;
    if (idx < 122880) {                        // qkvT[640][192]
        int col = idx / 192, k = idx % 192;
        qkvT[idx] = (col < 540 && k < 180) ? f2bf(qkv_w[k * 540 + col]) : (u16)0;
    } else if (idx < 172032) {                 // projT[256][192]
        int i = idx - 122880; int col = i / 192, k = i % 192;
        projT[i] = (col < 180 && k < 180) ? f2bf(proj_w[k * 180 + col]) : (u16)0;
    } else if (idx < 245760) {                 // fc1T[384][192]
        int i = idx - 172032; int col = i / 192, k = i % 192;
        fc1T[i] = (col < 360 && k < 180) ? f2bf(fc1_w[k * 360 + col]) : (u16)0;
    } else if (idx < 344064) {                 // fc2T[256][384]
        int i = idx - 245760; int col = i / 384, k = i % 384;
        fc2T[i] = (col < 180 && k < 360) ? f2bf(fc2_w[k * 180 + col]) : (u16)0;
    } else if (idx < 1228800) {                // bias5[(h*36+ch*4+mi)][lg][wv][l15][e]
        int i = idx - 344064;
        int e = i & 15, l15 = (i >> 4) & 15, wv2 = (i >> 8) & 3, lg2 = (i >> 10) & 3;
        int cm36 = i >> 12;
        int hh = cm36 / 36, cm = cm36 % 36;
        int ch = cm >> 2, mi = cm & 3;
        int ni = e >> 2, rr = e & 3;
        int q = wv2 * 64 + ni * 16 + l15;
        int key = ch * 64 + mi * 16 + lg2 * 4 + rr;
        bias5[i] = f2bf(rpb[rpi[q * 576 + key] * 6 + hh] * LOG2E);
    } else if (idx < 1628160) {                // K_pad border tokens (u32 x16)
        int i = idx - 1228800;
        int tok = i >> 4, wj = i & 15;
        int h = tok / 4160, b = tok % 4160, y, xx;
        border_yx(b, y, xx);
        kp_u32[((h * 264 + y) * 264 + xx) * 16 + wj] = 0u;
    } else if (idx < 2021376) {                // K_pad interior dims 30,31
        int i = idx - 1628160;
        int h = i / 65536, t = i % 65536;
        int y = t >> 8, xx = t & 255;
        kp_u32[((h * 264 + y + 4) * 264 + xx + 4) * 16 + 15] = 0u;
    } else if (idx < 2236800) {                // vP d=30 plane := 1.0
        int i = idx - 2021376;
        int h = i / 35904, r = i % 35904;
        vp_u32[(h * 32 + 30) * 35904 + r] = 0x3F803F80u;
    } else if (idx < 2452224) {                // vP d=31 plane := 0
        int i = idx - 2236800;
        int h = i / 35904, r = i % 35904;
        vp_u32[(h * 32 + 31) * 35904 + r] = 0u;
    } else if (idx < 3016704) {                // vP d<30 borders := 0
        int i = idx - 2452224;
        int hd = i / 3136, j = i % 3136;
        int h = hd / 30, d = hd % 30;
        int y, xu;
        if (j < 1088) { int r = j / 136; y = r + (r >= 4 ? 256 : 0); xu = j % 136; }
        else { int j2 = j - 1088; y = 4 + (j2 >> 3); int q = j2 & 7;
               xu = (q < 2) ? q : 128 + q; }
        vp_u32[((h * 32 + d) * 264 + y) * 136 + xu] = 0u;
    }
}

// ---------------------------------------------------------------------------
// LayerNorm over bf16 input [row][192] (x2 residual stream) -> bf16 [row][192]
// ---------------------------------------------------------------------------
__global__ __launch_bounds__(256)
void lnb_k(const u16* __restrict__ in, const float* __restrict__ w,
           const float* __restrict__ b, u16* __restrict__ out)
{
    int row = blockIdx.x * 4 + (threadIdx.x >> 6);
    int lane = threadIdx.x & 63;
    fvec4 v = {0.f, 0.f, 0.f, 0.f};
    if (lane < 45) {
        u16x4 raw = *(const u16x4*)(in + (long)row * 192 + lane * 4);
        #pragma unroll
        for (int j = 0; j < 4; j++) v[j] = bf2f(raw[j]);
    }
    float s  = v.x + v.y + v.z + v.w;
    float sq = v.x * v.x + v.y * v.y + v.z * v.z + v.w * v.w;
    for (int m = 1; m < 64; m <<= 1) { s += __shfl_xor(s, m); sq += __shfl_xor(sq, m); }
    float mean = s * (1.f / 180.f);
    float var  = sq * (1.f / 180.f) - mean * mean;
    float rstd = rsqrtf(var + 1e-5f);
    if (lane < 45) {
        u16x4 o;
        #pragma unroll
        for (int j = 0; j < 4; j++) {
            int c = lane * 4 + j;
            o[j] = f2bf((v[j] - mean) * rstd * w[c] + b[c]);
        }
        *(u16x4*)(out + (long)row * 192 + lane * 4) = o;
    } else if (lane < 48) {
        u16x4 z = {0, 0, 0, 0};
        *(u16x4*)(out + (long)row * 192 + 180 + (lane - 45) * 4) = z;
    }
}

// ---------------------------------------------------------------------------
// V transpose -> planar vP[h][32][264][272] (x shifted +4; 16B-aligned rows).
// ---------------------------------------------------------------------------
__global__ __launch_bounds__(256)
void vtr_k(const u16* __restrict__ v_s, u16* __restrict__ vP)
{
    __shared__ u16 tile[32][268];
    const int y = blockIdx.x, h = blockIdx.y;
    const int t = threadIdx.x;
    #pragma unroll
    for (int k2 = 0; k2 < 4; ++k2) {
        int u = t + k2 * 256;
        int x = u >> 2, dp = (u & 3) * 8;
        u16x8 v = *(const u16x8*)(v_s + (((long)(y * 256 + x)) * 6 + h) * 32 + dp);
        #pragma unroll
        for (int j = 0; j < 8; j++) tile[dp + j][x] = v[j];
    }
    __syncthreads();
    const long base = (((long)h * 32) * 264 + y + 4) * 272 + 4;
    #pragma unroll
    for (int k2 = 0; k2 < 4; ++k2) {
        int u = t + k2 * 256;
        if (u < 960) {
            int d = u >> 5, xg = u & 31;
            u16x4 a = *(const u16x4*)(&tile[d][xg * 8]);
            u16x4 b = *(const u16x4*)(&tile[d][xg * 8 + 4]);
            long dst = base + (long)d * (264 * 272) + xg * 8;
            *(u16x4*)(vP + dst) = a;
            *(u16x4*)(vP + dst + 4) = b;
        }
    }
}

// ---------------------------------------------------------------------------
// GEMM: 128x64 tile, 4 waves 2x2 (wave 64x32). B panel in registers, A
// double-buffered LDS, 1 barrier/K-step (r8 core). EPILOGUES REWRITTEN with
// explicit per-nd / per-mi hoisting (div/mod 2x per lane, not 32x).
// EPI: 0=qkv scatter, 1=proj(+bias+f32 resid -> bf16 x2), 2=fc1 gelu->bf16,
//      3=fc2(+bias+bf16 resid -> f32 out)
// ---------------------------------------------------------------------------
template<int KTOT, int EPI>
__global__ __launch_bounds__(256)
void gemm_k(const u16* __restrict__ A, const u16* __restrict__ Bt,
            const float* __restrict__ bias, const float* __restrict__ resid,
            void* __restrict__ o0, void* __restrict__ o1, void* __restrict__ o2)
{
    constexpr int NK = KTOT / 32;
    constexpr int GK = (NK > 6) ? 6 : NK;
    __shared__ u16 lds_a[2][128 * 32];
    const int tid = threadIdx.x;
    const int l = tid & 63, wv = tid >> 6;
    const int wm = wv >> 1, wn = wv & 1;
    const int l15 = l & 15, lg = l >> 4;
    const int swz = (lg ^ ((l15 >> 1) & 3)) * 8;
    const long rowb = (long)blockIdx.x * 128;
    const int colb = blockIdx.y * 64;
    const f32x4 fz = {0.f, 0.f, 0.f, 0.f};

    f32x4 acc[4][2];
    #pragma unroll
    for (int i = 0; i < 4; i++) { acc[i][0] = fz; acc[i][1] = fz; }

    const int r = tid >> 2, g = tid & 3;
    const int gsw = (g ^ ((r >> 1) & 3)) * 8;
    const u16* Ar0 = A + (rowb + r) * KTOT + gsw;
    const u16* Ar1 = A + (rowb + 64 + r) * KTOT + gsw;
    const u16* Bb  = Bt + (long)(colb + wn * 32 + l15) * KTOT + lg * 8;

    GLD16(Ar0, (char*)lds_a[0] + wv * 1024);
    GLD16(Ar1, (char*)lds_a[0] + 4096 + wv * 1024);

    for (int kg = 0; kg < NK; kg += GK) {
        bf16x8 bfr[2][GK];
        #pragma unroll
        for (int g2 = 0; g2 < GK; ++g2) {
            bfr[0][g2] = *(const bf16x8*)(Bb + (kg + g2) * 32);
            bfr[1][g2] = *(const bf16x8*)(Bb + 16 * KTOT + (kg + g2) * 32);
        }
        #pragma unroll
        for (int g2 = 0; g2 < GK; ++g2) {
            const int k = kg + g2;
            __syncthreads();
            if (k + 1 < NK) {
                GLD16(Ar0 + (k + 1) * 32, (char*)lds_a[(k + 1) & 1] + wv * 1024);
                GLD16(Ar1 + (k + 1) * 32, (char*)lds_a[(k + 1) & 1] + 4096 + wv * 1024);
            }
            const u16* la = lds_a[k & 1];
            bf16x8 af[4];
            #pragma unroll
            for (int mi = 0; mi < 4; mi++)
                af[mi] = *(const bf16x8*)(la + (wm * 64 + mi * 16 + l15) * 32 + swz);
            #pragma unroll
            for (int mi = 0; mi < 4; mi++)
                #pragma unroll
                for (int nd = 0; nd < 2; nd++)
                    acc[mi][nd] = __builtin_amdgcn_mfma_f32_16x16x32_bf16(af[mi], bfr[nd][g2], acc[mi][nd], 0, 0, 0);
        }
    }

    #pragma unroll
    for (int nd = 0; nd < 2; nd++) {
        const int c = colb + wn * 32 + nd * 16 + l15;
        if (EPI == 0) {
            if (c < 540) {
                const float bb = bias[c];
                const int sec = (c >= 360) ? 2 : ((c >= 180) ? 1 : 0);
                const int cc = c - sec * 180;
                const int hh = cc / 30, d = cc - hh * 30;
                #pragma unroll
                for (int mi = 0; mi < 4; mi++) {
                    const long t0 = rowb + wm * 64 + mi * 16 + lg * 4;
                    const int y = (int)(t0 >> 8), x0 = (int)(t0 & 255);
                    if (sec == 0) {
                        int win = ((y >> 4) << 4) | (x0 >> 4);
                        int qrow0 = ((y & 15) << 4) | (x0 & 15);
                        u16* dst = (u16*)o0 + (((long)(win * 6 + hh)) * 256 + qrow0) * 32 + d;
                        #pragma unroll
                        for (int rr = 0; rr < 4; rr++)
                            dst[rr * 32] = f2bf((acc[mi][nd][rr] + bb) * SCALE_Q2);
                    } else if (sec == 1) {
                        u16* dst = (u16*)o1 + (((long)hh * 264 + y + 4) * 264 + x0 + 4) * 32 + d;
                        #pragma unroll
                        for (int rr = 0; rr < 4; rr++)
                            dst[rr * 32] = f2bf(acc[mi][nd][rr] + bb);
                    } else {
                        u16* dst = (u16*)o2 + (t0 * 6 + hh) * 32 + d;
                        #pragma unroll
                        for (int rr = 0; rr < 4; rr++)
                            dst[rr * 192] = f2bf(acc[mi][nd][rr] + bb);
                    }
                }
            }
        } else if (EPI == 1) {          // proj: + bias + f32 resid -> bf16 x2
            if (c < 180) {
                const float bb = bias[c];
                #pragma unroll
                for (int mi = 0; mi < 4; mi++) {
                    const long t0 = rowb + wm * 64 + mi * 16 + lg * 4;
                    const float* rs = resid + t0 * 180 + c;
                    u16* dst = (u16*)o0 + t0 * 192 + c;
                    #pragma unroll
                    for (int rr = 0; rr < 4; rr++)
                        dst[rr * 192] = f2bf(acc[mi][nd][rr] + bb + rs[rr * 180]);
                }
            }
        } else if (EPI == 2) {          // fc1: gelu -> bf16 h1 [t][384]
            const float bb = (c < 360) ? bias[c] : 0.f;
            #pragma unroll
            for (int mi = 0; mi < 4; mi++) {
                const long t0 = rowb + wm * 64 + mi * 16 + lg * 4;
                u16* dst = (u16*)o0 + t0 * 384 + c;
                #pragma unroll
                for (int rr = 0; rr < 4; rr++) {
                    float xx = acc[mi][nd][rr] + bb;
                    float u2n = -2.f * xx * (0.7978845608f + 0.0356774081f * xx * xx);
                    dst[rr * 384] = f2bf(xx / (1.f + __expf(u2n)));
                }
            }
        } else {                        // fc2: + bias + bf16 resid -> f32 out
            if (c < 180) {
                const float bb = bias[c];
                const u16* x2b = (const u16*)o1;
                #pragma unroll
                for (int mi = 0; mi < 4; mi++) {
                    const long t0 = rowb + wm * 64 + mi * 16 + lg * 4;
                    const u16* rs = x2b + t0 * 192 + c;
                    float* dst = (float*)o0 + t0 * 180 + c;
                    #pragma unroll
                    for (int rr = 0; rr < 4; rr++)
                        dst[rr * 180] = acc[mi][nd][rr] + bb + bf2f(rs[rr * 192]);
                }
            }
        }
    }
}

// ---------------------------------------------------------------------------
// Attention (r8 core): block=(window,head), 4 waves x 64 q, 9 chunks of 64.
// Epilogue now packs via v_cvt_pk_bf16_f32 into 4B-aligned u32 stores.
// ---------------------------------------------------------------------------
__global__ __launch_bounds__(256)
void attn_k(const u16* __restrict__ q_g, const u16* __restrict__ K_pad,
            const u16* __restrict__ vP, const u16* __restrict__ bias5,
            u16* __restrict__ attn_out)
{
    __shared__ u16 kc[2][64 * 32];
    __shared__ u16 vt[2][32 * 64];

    const int w = ((blockIdx.x & 7) << 5) | (blockIdx.x >> 3);   // XCD swizzle
    const int h = blockIdx.y;
    const int wy = w >> 4, wx = w & 15;
    const int tid = threadIdx.x;
    const int wv = tid >> 6, l = tid & 63;
    const int l15 = l & 15, lg = l >> 4;
    const int swzk = (l15 >> 1) & 3;
    const int swzv = l15 & 7;

    bf16x8 qb[4];
    #pragma unroll
    for (int ni = 0; ni < 4; ni++) {
        int qrow = wv * 64 + ni * 16 + l15;
        qb[ni] = *(const bf16x8*)(q_g + (((long)(w * 6 + h)) * 256 + qrow) * 32 + lg * 8);
    }

    f32x4 acc[2][4];
    #pragma unroll
    for (int i = 0; i < 2; i++)
        #pragma unroll
        for (int j = 0; j < 4; j++) acc[i][j] = (f32x4){0.f, 0.f, 0.f, 0.f};

    const int tK = tid >> 2;
    const int gtk = (l & 3) ^ ((l >> 3) & 3);
    const int aK = (tK >= 48) ? 2 : (tK >= 24 ? 1 : 0);
    const int bK = tK - aK * 24;
    const u16* KbaseRow = K_pad + (((long)(h * 264 + wy * 16)) * 264 + wx * 16) * 32 + gtk * 8;
    const int dV = tid >> 3;
    const int gtv = (l & 7) ^ (l >> 3);
    const int aV = gtv / 3, bV = (gtv % 3) * 8;
    const u16* Vrow0 = vP + ((((long)h * 32 + dV) * 264) + wy * 16) * 272 + wx * 16;
    const u16* Bp = bias5 + (long)h * 147456 + ((lg * 4 + wv) * 16 + l15) * 16;

    GLD16(KbaseRow + ((long)aK * 264 + bK) * 32, (char*)kc[0] + wv * 1024);
    GLD16(Vrow0 + aV * 272 + bV, (char*)vt[0] + wv * 1024);

    #pragma unroll
    for (int ch = 0; ch < 9; ++ch) {
        __syncthreads();
        u16x8 bl[4], bh[4];
        #pragma unroll
        for (int mi = 0; mi < 4; mi++) {
            bl[mi] = *(const u16x8*)(Bp + (ch * 4 + mi) * 4096);
            bh[mi] = *(const u16x8*)(Bp + (ch * 4 + mi) * 4096 + 8);
        }
        if (ch < 8) {
            int n = (ch + 1) * 64;
            int c1 = n / 24, c2 = n - c1 * 24;
            int bb2 = bK + c2;
            int t2 = bb2 >= 24;
            int oy = c1 + aK + t2, ox = bb2 - (t2 ? 24 : 0);
            GLD16(KbaseRow + ((long)oy * 264 + ox) * 32, (char*)kc[(ch + 1) & 1] + wv * 1024);
            int bbv = bV + c2;
            int t2v = bbv >= 24;
            int oyv = c1 + aV + t2v, oxv = bbv - (t2v ? 24 : 0);
            GLD16(Vrow0 + oyv * 272 + oxv, (char*)vt[(ch + 1) & 1] + wv * 1024);
        }
        const u16* kcur = kc[ch & 1];
        const u16* vcur = vt[ch & 1];

        #pragma unroll
        for (int ks = 0; ks < 2; ++ks) {
            int Wp[2][4][2];
            #pragma unroll
            for (int mih = 0; mih < 2; ++mih) {
                int mi = ks * 2 + mih;
                int key = ks * 32 + mih * 16 + l15;
                bf16x8 ka = *(const bf16x8*)(kcur + key * 32 + (lg ^ swzk) * 8);
                union { u16x8 v; unsigned d[4]; } ulo, uhi;
                ulo.v = bl[mi]; uhi.v = bh[mi];
                f32x4 s[4];
                #pragma unroll
                for (int ni = 0; ni < 4; ni++) {
                    unsigned dA = (ni < 2) ? ulo.d[(ni & 1) * 2]     : uhi.d[(ni & 1) * 2];
                    unsigned dB = (ni < 2) ? ulo.d[(ni & 1) * 2 + 1] : uhi.d[(ni & 1) * 2 + 1];
                    f32x4 ci;
                    ci[0] = __uint_as_float(dA << 16);
                    ci[1] = __uint_as_float(dA & 0xFFFF0000u);
                    ci[2] = __uint_as_float(dB << 16);
                    ci[3] = __uint_as_float(dB & 0xFFFF0000u);
                    s[ni] = ci;
                }
                #pragma unroll
                for (int ni = 0; ni < 4; ni++)
                    s[ni] = __builtin_amdgcn_mfma_f32_16x16x32_bf16(ka, qb[ni], s[ni], 0, 0, 0);
                #pragma unroll
                for (int ni = 0; ni < 4; ni++) {
                    float p0 = exp2_raw(s[ni][0]);
                    float p1 = exp2_raw(s[ni][1]);
                    float p2 = exp2_raw(s[ni][2]);
                    float p3 = exp2_raw(s[ni][3]);
                    Wp[mih][ni][0] = (int)pk_bf16(p0, p1);
                    Wp[mih][ni][1] = (int)pk_bf16(p2, p3);
                }
            }
            bf16x8 va0 = *(const bf16x8*)(vcur + l15 * 64 + ((ks * 4 + lg) ^ swzv) * 8);
            bf16x8 va1 = *(const bf16x8*)(vcur + (16 + l15) * 64 + ((ks * 4 + lg) ^ swzv) * 8);
            #pragma unroll
            for (int ni = 0; ni < 4; ni++) {
                i32x2 r0 = __builtin_amdgcn_permlane32_swap(Wp[0][ni][0], Wp[1][ni][0], false, false);
                i32x2 r1 = __builtin_amdgcn_permlane32_swap(Wp[0][ni][1], Wp[1][ni][1], false, false);
                int wd0, wd1, wd2, wd3;
                xswap16(r0[0], r0[1], wd0, wd2);
                xswap16(r1[0], r1[1], wd1, wd3);
                union { int wd[4]; bf16x8 v; } pu;
                pu.wd[0] = wd0; pu.wd[1] = wd1; pu.wd[2] = wd2; pu.wd[3] = wd3;
                acc[0][ni] = __builtin_amdgcn_mfma_f32_16x16x32_bf16(va0, pu.v, acc[0][ni], 0, 0, 0);
                acc[1][ni] = __builtin_amdgcn_mfma_f32_16x16x32_bf16(va1, pu.v, acc[1][ni], 0, 0, 0);
            }
        }
    }

    // epilogue: O^T row d=30 holds sum(P); divide, pack bf16 pairs, u32 stores
    #pragma unroll
    for (int ni = 0; ni < 4; ni++) {
        float sum = __shfl(acc[1][ni][2], 48 + l15);
        float inv = 1.f / sum;
        int q = wv * 64 + ni * 16 + l15;
        int y = wy * 16 + (q >> 4), x = wx * 16 + (q & 15);
        u16* bp = attn_out + ((long)(y * 256 + x)) * 192 + h * 30;
        unsigned w0 = pk_bf16(acc[0][ni][0] * inv, acc[0][ni][1] * inv);
        unsigned w1 = pk_bf16(acc[0][ni][2] * inv, acc[0][ni][3] * inv);
        *(unsigned*)(bp + lg * 4)     = w0;
        *(unsigned*)(bp + lg * 4 + 2) = w1;
        unsigned w2 = pk_bf16(acc[1][ni][0] * inv, acc[1][ni][1] * inv);
        if (lg < 3) {
            unsigned w3 = pk_bf16(acc[1][ni][2] * inv, acc[1][ni][3] * inv);
            *(unsigned*)(bp + 16 + lg * 4)     = w2;
            *(unsigned*)(bp + 16 + lg * 4 + 2) = w3;
        } else {
            *(unsigned*)(bp + 28) = w2;   // dims 28,29 only (30 is the sum row)
        }
    }
}

// ---------------------------------------------------------------------------
extern "C" void kernel_launch(void* const* d_in, const int* in_sizes, int n_in,
                              void* d_out, int out_size, void* d_ws, size_t ws_size,
                              hipStream_t stream)
{
    (void)in_sizes; (void)n_in; (void)out_size; (void)ws_size;
    const float* x      = (const float*)d_in[0];
    const int*   rpi    = (const int*)d_in[1];
    const float* n1w    = (const float*)d_in[2];
    const float* n1b    = (const float*)d_in[3];
    const float* qkv_w  = (const float*)d_in[4];
    const float* qkv_b  = (const float*)d_in[5];
    const float* rpb    = (const float*)d_in[6];
    const float* proj_w = (const float*)d_in[7];
    const float* proj_b = (const float*)d_in[8];
    const float* n2w    = (const float*)d_in[9];
    const float* n2b    = (const float*)d_in[10];
    const float* fc1_w  = (const float*)d_in[11];
    const float* fc1_b  = (const float*)d_in[12];
    const float* fc2_w  = (const float*)d_in[13];
    const float* fc2_b  = (const float*)d_in[14];
    float* out = (float*)d_out;

    char* ws = (char*)d_ws;
    size_t off = 0;
    auto alloc = [&](size_t bytes) -> void* {
        void* p = ws + off; off += (bytes + 511) & ~(size_t)511; return p;
    };
    u16*   xn     = (u16*)alloc(65536ull * 192 * 2);        // ln out; ao aliases
    u16*   q_g    = (u16*)alloc(65536ull * 192 * 2);        // [win][h][q][32]
    u16*   K_pad  = (u16*)alloc(6ull * 264 * 264 * 32 * 2); // [h][y][x][32]
    u16*   v_s    = (u16*)alloc(65536ull * 180 * 4);        // aliased with x2b
    u16*   x2b    = v_s;                                    // bf16 [t][192]; v_s dead before proj
    u16*   vP     = (u16*)alloc(6ull * 32 * 264 * 272 * 2); // [h][d][y+4][x+4]
    u16*   bias5  = (u16*)alloc(6ull * 36 * 4 * 4 * 16 * 16 * 2);
    u16*   qkvT   = (u16*)alloc(640ull * 192 * 2);
    u16*   projT  = (u16*)alloc(256ull * 192 * 2);
    u16*   fc1T   = (u16*)alloc(384ull * 192 * 2);
    u16*   fc2T   = (u16*)alloc(256ull * 384 * 2);
    u16*   ao     = xn;    // ln1 zero-fills cols 180..191; attn fills 0..179
    u16*   h1     = q_g;   // fc1 out [t][384]: q_g+K_pad adjacent >= 50.3MB

    prepln_k<<<dim3(28168), dim3(256), 0, stream>>>(x, n1w, n1b, xn,
        qkv_w, proj_w, fc1_w, fc2_w, rpi, rpb,
        qkvT, projT, fc1T, fc2T, bias5, (unsigned*)K_pad, (unsigned*)vP);
    gemm_k<192, 0><<<dim3(512, 9), dim3(256), 0, stream>>>(
        xn, qkvT, qkv_b, (const float*)nullptr, q_g, K_pad, v_s);
    vtr_k<<<dim3(256, 6), dim3(256), 0, stream>>>(v_s, vP);
    attn_k<<<dim3(256, 6), dim3(256), 0, stream>>>(q_g, K_pad, vP, bias5, ao);
    gemm_k<192, 1><<<dim3(512, 3), dim3(256), 0, stream>>>(
        ao, projT, proj_b, x, x2b, nullptr, nullptr);
    lnb_k<<<dim3(16384), dim3(256), 0, stream>>>(x2b, n2w, n2b, xn);
    gemm_k<192, 2><<<dim3(512, 6), dim3(256), 0, stream>>>(
        xn, fc1T, fc1_b, (const float*)nullptr, h1, nullptr, nullptr);
    gemm_k<384, 3><<<dim3(512, 3), dim3(256), 0, stream>>>(
        h1, fc2T, fc2_b, (const float*)nullptr, out, x2b, nullptr);
}

// Round 10
// 268.748 us; speedup vs baseline: 1.1941x; 1.0712x over previous
//
#include <hip/hip_runtime.h>

typedef float f32x4 __attribute__((ext_vector_type(4)));
typedef float fvec4 __attribute__((ext_vector_type(4)));
typedef __bf16 bf16x8 __attribute__((ext_vector_type(8)));
typedef unsigned short u16;
typedef u16 u16x8 __attribute__((ext_vector_type(8)));
typedef u16 u16x4 __attribute__((ext_vector_type(4)));
typedef int i32x2 __attribute__((ext_vector_type(2)));

#define SCALE_Q 0.18257418583505536f   /* 30^-0.5 */
#define LOG2E   1.4426950408889634f
#define SCALE_Q2 (SCALE_Q * LOG2E)     /* folded: exp(s) = 2^(s*log2e) */

__device__ __forceinline__ u16 f2bf(float f) {
    union { __bf16 h; u16 u; } cv; cv.h = (__bf16)f; return cv.u;
}
__device__ __forceinline__ float bf2f(u16 u) {
    union { __bf16 h; u16 u; } cv; cv.u = u; return (float)cv.h;
}
__device__ __forceinline__ float exp2_raw(float x) {
    float r;
    asm("v_exp_f32 %0, %1" : "=v"(r) : "v"(x));
    return r;
}
__device__ __forceinline__ unsigned pk_bf16(float a, float b) {
    unsigned r;
    asm("v_cvt_pk_bf16_f32 %0, %1, %2" : "=v"(r) : "v"(a), "v"(b));
    return r;
}

// async global->LDS, 16B per lane; LDS dest = wave-uniform base + lane*16
#define GLD16(gsrc, ldst) __builtin_amdgcn_global_load_lds( \
    (const __attribute__((address_space(1))) unsigned*)(gsrc), \
    (__attribute__((address_space(3))) unsigned*)(ldst), 16, 0, 0)

// lane^16 cross-exchange pair
__device__ __forceinline__ void xswap16(int a, int b, int& u, int& v) {
#if __has_builtin(__builtin_amdgcn_permlane16_swap)
    i32x2 r = __builtin_amdgcn_permlane16_swap(a, b, false, false);
    u = r[0]; v = r[1];
#else
    int sa = __builtin_amdgcn_ds_swizzle(a, 0x401F);
    int sb = __builtin_amdgcn_ds_swizzle(b, 0x401F);
    bool hi = (threadIdx.x & 16) != 0;
    u = hi ? sb : a;
    v = hi ? b : sa;
#endif
}

// ---------------------------------------------------------------------------
// prep + ln1 merged (r9)
// ---------------------------------------------------------------------------
__device__ __forceinline__ void border_yx(int i, int& y, int& x) {
    if (i < 1056)      { y = i / 264; x = i % 264; }
    else if (i < 2112) { int j = i - 1056; y = 260 + j / 264; x = j % 264; }
    else               { int j = i - 2112; y = 4 + (j >> 3); int xx = j & 7;
                         x = (xx < 4) ? xx : 256 + xx; }
}

__global__ __launch_bounds__(256)
void prepln_k(const float* __restrict__ x, const float* __restrict__ n1w,
              const float* __restrict__ n1b, u16* __restrict__ xn,
              const float* __restrict__ qkv_w, const float* __restrict__ proj_w,
              const float* __restrict__ fc1_w, const float* __restrict__ fc2_w,
              const int* __restrict__ rpi, const float* __restrict__ rpb,
              u16* __restrict__ qkvT, u16* __restrict__ projT,
              u16* __restrict__ fc1T, u16* __restrict__ fc2T,
              u16* __restrict__ bias5, unsigned* __restrict__ kp_u32,
              unsigned* __restrict__ vp_u32)
{
    if (blockIdx.x < 16384) {      // ----- LayerNorm1 -----
        int row = blockIdx.x * 4 + (threadIdx.x >> 6);
        int lane = threadIdx.x & 63;
        fvec4 v = {0.f, 0.f, 0.f, 0.f};
        if (lane < 45) v = *(const fvec4*)(x + (long)row * 180 + lane * 4);
        float s  = v.x + v.y + v.z + v.w;
        float sq = v.x * v.x + v.y * v.y + v.z * v.z + v.w * v.w;
        for (int m = 1; m < 64; m <<= 1) { s += __shfl_xor(s, m); sq += __shfl_xor(sq, m); }
        float mean = s * (1.f / 180.f);
        float var  = sq * (1.f / 180.f) - mean * mean;
        float rstd = rsqrtf(var + 1e-5f);
        if (lane < 45) {
            u16x4 o;
            #pragma unroll
            for (int j = 0; j < 4; j++) {
                int c = lane * 4 + j;
                o[j] = f2bf((v[j] - mean) * rstd * n1w[c] + n1b[c]);
            }
            *(u16x4*)(xn + (long)row * 192 + lane * 4) = o;
        } else if (lane < 48) {
            u16x4 z = {0, 0, 0, 0};
            *(u16x4*)(xn + (long)row * 192 + 180 + (lane - 45) * 4) = z;
        }
        return;
    }
    int idx = (blockIdx.x - 16384) * 256 + threadIdx.x;
    if (idx < 122880) {                        // qkvT[640][192]
        int col = idx / 192, k = idx % 192;
        qkvT[idx] = (col < 540 && k < 180) ? f2bf(qkv_w[k * 540 + col]) : (u16)0;
    } else if (idx < 172032) {                 // projT[256][192]
        int i = idx - 122880; int col = i / 192, k = i % 192;
        projT[i] = (col < 180 && k < 180) ? f2bf(proj_w[k * 180 + col]) : (u16)0;
    } else if (idx < 245760) {                 // fc1T[384][192]
        int i = idx - 172032; int col = i / 192, k = i % 192;
        fc1T[i] = (col < 360 && k < 180) ? f2bf(fc1_w[k * 360 + col]) : (u16)0;
    } else if (idx < 344064) {                 // fc2T[256][384]
        int i = idx - 245760; int col = i / 384, k = i % 384;
        fc2T[i] = (col < 180 && k < 360) ? f2bf(fc2_w[k * 180 + col]) : (u16)0;
    } else if (idx < 1228800) {                // bias5[(h*36+ch*4+mi)][lg][wv][l15][e]
        int i = idx - 344064;
        int e = i & 15, l15 = (i >> 4) & 15, wv2 = (i >> 8) & 3, lg2 = (i >> 10) & 3;
        int cm36 = i >> 12;
        int hh = cm36 / 36, cm = cm36 % 36;
        int ch = cm >> 2, mi = cm & 3;
        int ni = e >> 2, rr = e & 3;
        int q = wv2 * 64 + ni * 16 + l15;
        int key = ch * 64 + mi * 16 + lg2 * 4 + rr;
        bias5[i] = f2bf(rpb[rpi[q * 576 + key] * 6 + hh] * LOG2E);
    } else if (idx < 1628160) {                // K_pad border tokens (u32 x16)
        int i = idx - 1228800;
        int tok = i >> 4, wj = i & 15;
        int h = tok / 4160, b = tok % 4160, y, xx;
        border_yx(b, y, xx);
        kp_u32[((h * 264 + y) * 264 + xx) * 16 + wj] = 0u;
    } else if (idx < 2021376) {                // K_pad interior dims 30,31
        int i = idx - 1628160;
        int h = i / 65536, t = i % 65536;
        int y = t >> 8, xx = t & 255;
        kp_u32[((h * 264 + y + 4) * 264 + xx + 4) * 16 + 15] = 0u;
    } else if (idx < 2236800) {                // vP d=30 plane := 1.0
        int i = idx - 2021376;
        int h = i / 35904, r = i % 35904;
        vp_u32[(h * 32 + 30) * 35904 + r] = 0x3F803F80u;
    } else if (idx < 2452224) {                // vP d=31 plane := 0
        int i = idx - 2236800;
        int h = i / 35904, r = i % 35904;
        vp_u32[(h * 32 + 31) * 35904 + r] = 0u;
    } else if (idx < 3016704) {                // vP d<30 borders := 0
        int i = idx - 2452224;
        int hd = i / 3136, j = i % 3136;
        int h = hd / 30, d = hd % 30;
        int y, xu;
        if (j < 1088) { int r = j / 136; y = r + (r >= 4 ? 256 : 0); xu = j % 136; }
        else { int j2 = j - 1088; y = 4 + (j2 >> 3); int q = j2 & 7;
               xu = (q < 2) ? q : 128 + q; }
        vp_u32[((h * 32 + d) * 264 + y) * 136 + xu] = 0u;
    }
}

// ---------------------------------------------------------------------------
// LayerNorm over bf16 input (x2 residual stream) -> bf16 [row][192]
// ---------------------------------------------------------------------------
__global__ __launch_bounds__(256)
void lnb_k(const u16* __restrict__ in, const float* __restrict__ w,
           const float* __restrict__ b, u16* __restrict__ out)
{
    int row = blockIdx.x * 4 + (threadIdx.x >> 6);
    int lane = threadIdx.x & 63;
    fvec4 v = {0.f, 0.f, 0.f, 0.f};
    if (lane < 45) {
        u16x4 raw = *(const u16x4*)(in + (long)row * 192 + lane * 4);
        #pragma unroll
        for (int j = 0; j < 4; j++) v[j] = bf2f(raw[j]);
    }
    float s  = v.x + v.y + v.z + v.w;
    float sq = v.x * v.x + v.y * v.y + v.z * v.z + v.w * v.w;
    for (int m = 1; m < 64; m <<= 1) { s += __shfl_xor(s, m); sq += __shfl_xor(sq, m); }
    float mean = s * (1.f / 180.f);
    float var  = sq * (1.f / 180.f) - mean * mean;
    float rstd = rsqrtf(var + 1e-5f);
    if (lane < 45) {
        u16x4 o;
        #pragma unroll
        for (int j = 0; j < 4; j++) {
            int c = lane * 4 + j;
            o[j] = f2bf((v[j] - mean) * rstd * w[c] + b[c]);
        }
        *(u16x4*)(out + (long)row * 192 + lane * 4) = o;
    } else if (lane < 48) {
        u16x4 z = {0, 0, 0, 0};
        *(u16x4*)(out + (long)row * 192 + 180 + (lane - 45) * 4) = z;
    }
}

// ---------------------------------------------------------------------------
// V transpose -> planar vP[h][32][264][272] (x shifted +4; 16B-aligned rows).
// ---------------------------------------------------------------------------
__global__ __launch_bounds__(256)
void vtr_k(const u16* __restrict__ v_s, u16* __restrict__ vP)
{
    __shared__ u16 tile[32][268];
    const int y = blockIdx.x, h = blockIdx.y;
    const int t = threadIdx.x;
    #pragma unroll
    for (int k2 = 0; k2 < 4; ++k2) {
        int u = t + k2 * 256;
        int x = u >> 2, dp = (u & 3) * 8;
        u16x8 v = *(const u16x8*)(v_s + (((long)(y * 256 + x)) * 6 + h) * 32 + dp);
        #pragma unroll
        for (int j = 0; j < 8; j++) tile[dp + j][x] = v[j];
    }
    __syncthreads();
    const long base = (((long)h * 32) * 264 + y + 4) * 272 + 4;
    #pragma unroll
    for (int k2 = 0; k2 < 4; ++k2) {
        int u = t + k2 * 256;
        if (u < 960) {
            int d = u >> 5, xg = u & 31;
            u16x4 a = *(const u16x4*)(&tile[d][xg * 8]);
            u16x4 b = *(const u16x4*)(&tile[d][xg * 8 + 4]);
            long dst = base + (long)d * (264 * 272) + xg * 8;
            *(u16x4*)(vP + dst) = a;
            *(u16x4*)(vP + dst + 4) = b;
        }
    }
}

// ---------------------------------------------------------------------------
// A-resident GEMM: block = one 128-row panel. A (128 x 192) staged ONCE into
// 48KB LDS (swizzle gp=(g&24)|((g&7)^(row&7)) -> conflict-free b128 reads at
// 384B row stride), then loop NCB 64-col blocks with B straight to registers
// (L2-hot) and ZERO barriers in the compute phase. For K=384 (fc2): two
// K-halves, acc[NCB] persistent, 3 barriers total.
// EPI: 0=qkv scatter, 1=proj(+bias+f32 resid->bf16), 2=fc1 gelu->bf16,
//      3=fc2(+bias+bf16 resid->f32 out)
// ---------------------------------------------------------------------------
template<int KTOT, int NCB, int EPI>
__global__ __launch_bounds__(256)
void gemm_k(const u16* __restrict__ A, const u16* __restrict__ Bt,
            const float* __restrict__ bias, const float* __restrict__ resid,
            void* __restrict__ o0, void* __restrict__ o1, void* __restrict__ o2)
{
    constexpr int NH = KTOT / 192;             // K-halves (1 or 2)
    constexpr int AC = (NH == 1) ? 1 : NCB;    // persistent acc sets
    __shared__ u16 lds_a[128 * 192];           // 48 KB
    const int tid = threadIdx.x;
    const int l = tid & 63, wv = tid >> 6;
    const int wm = wv >> 1, wn = wv & 1;
    const int l15 = l & 15, lg = l >> 4;
    const int rx7 = l15 & 7;
    const long rowb = (long)blockIdx.x * 128;
    const f32x4 fz = {0.f, 0.f, 0.f, 0.f};

    f32x4 acc[AC][4][2];
    #pragma unroll
    for (int a2 = 0; a2 < AC; a2++)
        #pragma unroll
        for (int i = 0; i < 4; i++) { acc[a2][i][0] = fz; acc[a2][i][1] = fz; }

    // per-lane A fragment row bases (u16 offsets; row stride 192)
    const u16* aptr[4];
    #pragma unroll
    for (int mi = 0; mi < 4; mi++)
        aptr[mi] = lds_a + (wm * 64 + mi * 16 + l15) * 192;

    auto epilogue = [&](int cb, f32x4 (&ac)[4][2]) {
        #pragma unroll
        for (int nd = 0; nd < 2; nd++) {
            const int c = cb * 64 + wn * 32 + nd * 16 + l15;
            if (EPI == 0) {
                if (c < 540) {
                    const float bb = bias[c];
                    const int sec = (c >= 360) ? 2 : ((c >= 180) ? 1 : 0);
                    const int cc = c - sec * 180;
                    const int hh = cc / 30, d = cc - hh * 30;
                    #pragma unroll
                    for (int mi = 0; mi < 4; mi++) {
                        const long t0 = rowb + wm * 64 + mi * 16 + lg * 4;
                        const int y = (int)(t0 >> 8), x0 = (int)(t0 & 255);
                        if (sec == 0) {
                            int win = ((y >> 4) << 4) | (x0 >> 4);
                            int qrow0 = ((y & 15) << 4) | (x0 & 15);
                            u16* dst = (u16*)o0 + (((long)(win * 6 + hh)) * 256 + qrow0) * 32 + d;
                            #pragma unroll
                            for (int rr = 0; rr < 4; rr++)
                                dst[rr * 32] = f2bf((ac[mi][nd][rr] + bb) * SCALE_Q2);
                        } else if (sec == 1) {
                            u16* dst = (u16*)o1 + (((long)hh * 264 + y + 4) * 264 + x0 + 4) * 32 + d;
                            #pragma unroll
                            for (int rr = 0; rr < 4; rr++)
                                dst[rr * 32] = f2bf(ac[mi][nd][rr] + bb);
                        } else {
                            u16* dst = (u16*)o2 + (t0 * 6 + hh) * 32 + d;
                            #pragma unroll
                            for (int rr = 0; rr < 4; rr++)
                                dst[rr * 192] = f2bf(ac[mi][nd][rr] + bb);
                        }
                    }
                }
            } else if (EPI == 1) {
                if (c < 180) {
                    const float bb = bias[c];
                    #pragma unroll
                    for (int mi = 0; mi < 4; mi++) {
                        const long t0 = rowb + wm * 64 + mi * 16 + lg * 4;
                        const float* rs = resid + t0 * 180 + c;
                        u16* dst = (u16*)o0 + t0 * 192 + c;
                        #pragma unroll
                        for (int rr = 0; rr < 4; rr++)
                            dst[rr * 192] = f2bf(ac[mi][nd][rr] + bb + rs[rr * 180]);
                    }
                }
            } else if (EPI == 2) {
                const float bb = (c < 360) ? bias[c] : 0.f;
                #pragma unroll
                for (int mi = 0; mi < 4; mi++) {
                    const long t0 = rowb + wm * 64 + mi * 16 + lg * 4;
                    u16* dst = (u16*)o0 + t0 * 384 + c;
                    #pragma unroll
                    for (int rr = 0; rr < 4; rr++) {
                        float xx = ac[mi][nd][rr] + bb;
                        float u2n = -2.f * xx * (0.7978845608f + 0.0356774081f * xx * xx);
                        dst[rr * 384] = f2bf(xx / (1.f + __expf(u2n)));
                    }
                }
            } else {
                if (c < 180) {
                    const float bb = bias[c];
                    const u16* x2b = (const u16*)o1;
                    #pragma unroll
                    for (int mi = 0; mi < 4; mi++) {
                        const long t0 = rowb + wm * 64 + mi * 16 + lg * 4;
                        const u16* rs = x2b + t0 * 192 + c;
                        float* dst = (float*)o0 + t0 * 180 + c;
                        #pragma unroll
                        for (int rr = 0; rr < 4; rr++)
                            dst[rr * 180] = ac[mi][nd][rr] + bb + bf2f(rs[rr * 192]);
                    }
                }
            }
        }
    };

    #pragma unroll
    for (int hk = 0; hk < NH; ++hk) {
        if (hk) __syncthreads();               // all waves done with prev half
        // stage A half hk: 12 GLD16/thread, inverse-swizzled source
        #pragma unroll
        for (int R = 0; R < 12; ++R) {
            int idx = R * 256 + tid;
            int row = idx / 24, gp = idx - row * 24;
            int g = (gp & 24) | ((gp & 7) ^ (row & 7));
            GLD16(A + (rowb + row) * KTOT + hk * 192 + g * 8,
                  (char*)lds_a + R * 4096 + wv * 1024);
        }
        __syncthreads();                       // A half ready (drains vmcnt)

        for (int cb = 0; cb < NCB; ++cb) {
            f32x4 (&ac)[4][2] = acc[(NH == 1) ? 0 : cb];
            const u16* Bb = Bt + (long)(cb * 64 + wn * 32 + l15) * KTOT + hk * 192 + lg * 8;
            #pragma unroll
            for (int kg = 0; kg < 6; kg += 3) {
                bf16x8 bfr[2][3];
                #pragma unroll
                for (int g2 = 0; g2 < 3; ++g2) {
                    bfr[0][g2] = *(const bf16x8*)(Bb + (kg + g2) * 32);
                    bfr[1][g2] = *(const bf16x8*)(Bb + 16 * KTOT + (kg + g2) * 32);
                }
                #pragma unroll
                for (int g2 = 0; g2 < 3; ++g2) {
                    const int k = kg + g2;
                    const int gk = k * 4 + lg;
                    const int gpk = (gk & 24) | ((gk & 7) ^ rx7);
                    bf16x8 af[4];
                    #pragma unroll
                    for (int mi = 0; mi < 4; mi++)
                        af[mi] = *(const bf16x8*)(aptr[mi] + gpk * 8);
                    #pragma unroll
                    for (int mi = 0; mi < 4; mi++)
                        #pragma unroll
                        for (int nd = 0; nd < 2; nd++)
                            ac[mi][nd] = __builtin_amdgcn_mfma_f32_16x16x32_bf16(af[mi], bfr[nd][g2], ac[mi][nd], 0, 0, 0);
                }
            }
            if (NH == 1) {
                epilogue(cb, ac);
                #pragma unroll
                for (int i = 0; i < 4; i++) { ac[i][0] = fz; ac[i][1] = fz; }
            }
        }
    }
    if (NH == 2) {
        for (int cb = 0; cb < NCB; ++cb) epilogue(cb, acc[cb]);
    }
}

// ---------------------------------------------------------------------------
// Attention (r9, unchanged): block=(window,head), 4 waves x 64 q, 9 chunks.
// ---------------------------------------------------------------------------
__global__ __launch_bounds__(256)
void attn_k(const u16* __restrict__ q_g, const u16* __restrict__ K_pad,
            const u16* __restrict__ vP, const u16* __restrict__ bias5,
            u16* __restrict__ attn_out)
{
    __shared__ u16 kc[2][64 * 32];
    __shared__ u16 vt[2][32 * 64];

    const int w = ((blockIdx.x & 7) << 5) | (blockIdx.x >> 3);   // XCD swizzle
    const int h = blockIdx.y;
    const int wy = w >> 4, wx = w & 15;
    const int tid = threadIdx.x;
    const int wv = tid >> 6, l = tid & 63;
    const int l15 = l & 15, lg = l >> 4;
    const int swzk = (l15 >> 1) & 3;
    const int swzv = l15 & 7;

    bf16x8 qb[4];
    #pragma unroll
    for (int ni = 0; ni < 4; ni++) {
        int qrow = wv * 64 + ni * 16 + l15;
        qb[ni] = *(const bf16x8*)(q_g + (((long)(w * 6 + h)) * 256 + qrow) * 32 + lg * 8);
    }

    f32x4 acc[2][4];
    #pragma unroll
    for (int i = 0; i < 2; i++)
        #pragma unroll
        for (int j = 0; j < 4; j++) acc[i][j] = (f32x4){0.f, 0.f, 0.f, 0.f};

    const int tK = tid >> 2;
    const int gtk = (l & 3) ^ ((l >> 3) & 3);
    const int aK = (tK >= 48) ? 2 : (tK >= 24 ? 1 : 0);
    const int bK = tK - aK * 24;
    const u16* KbaseRow = K_pad + (((long)(h * 264 + wy * 16)) * 264 + wx * 16) * 32 + gtk * 8;
    const int dV = tid >> 3;
    const int gtv = (l & 7) ^ (l >> 3);
    const int aV = gtv / 3, bV = (gtv % 3) * 8;
    const u16* Vrow0 = vP + ((((long)h * 32 + dV) * 264) + wy * 16) * 272 + wx * 16;
    const u16* Bp = bias5 + (long)h * 147456 + ((lg * 4 + wv) * 16 + l15) * 16;

    GLD16(KbaseRow + ((long)aK * 264 + bK) * 32, (char*)kc[0] + wv * 1024);
    GLD16(Vrow0 + aV * 272 + bV, (char*)vt[0] + wv * 1024);

    #pragma unroll
    for (int ch = 0; ch < 9; ++ch) {
        __syncthreads();
        u16x8 bl[4], bh[4];
        #pragma unroll
        for (int mi = 0; mi < 4; mi++) {
            bl[mi] = *(const u16x8*)(Bp + (ch * 4 + mi) * 4096);
            bh[mi] = *(const u16x8*)(Bp + (ch * 4 + mi) * 4096 + 8);
        }
        if (ch < 8) {
            int n = (ch + 1) * 64;
            int c1 = n / 24, c2 = n - c1 * 24;
            int bb2 = bK + c2;
            int t2 = bb2 >= 24;
            int oy = c1 + aK + t2, ox = bb2 - (t2 ? 24 : 0);
            GLD16(KbaseRow + ((long)oy * 264 + ox) * 32, (char*)kc[(ch + 1) & 1] + wv * 1024);
            int bbv = bV + c2;
            int t2v = bbv >= 24;
            int oyv = c1 + aV + t2v, oxv = bbv - (t2v ? 24 : 0);
            GLD16(Vrow0 + oyv * 272 + oxv, (char*)vt[(ch + 1) & 1] + wv * 1024);
        }
        const u16* kcur = kc[ch & 1];
        const u16* vcur = vt[ch & 1];

        #pragma unroll
        for (int ks = 0; ks < 2; ++ks) {
            int Wp[2][4][2];
            #pragma unroll
            for (int mih = 0; mih < 2; ++mih) {
                int mi = ks * 2 + mih;
                int key = ks * 32 + mih * 16 + l15;
                bf16x8 ka = *(const bf16x8*)(kcur + key * 32 + (lg ^ swzk) * 8);
                union { u16x8 v; unsigned d[4]; } ulo, uhi;
                ulo.v = bl[mi]; uhi.v = bh[mi];
                f32x4 s[4];
                #pragma unroll
                for (int ni = 0; ni < 4; ni++) {
                    unsigned dA = (ni < 2) ? ulo.d[(ni & 1) * 2]     : uhi.d[(ni & 1) * 2];
                    unsigned dB = (ni < 2) ? ulo.d[(ni & 1) * 2 + 1] : uhi.d[(ni & 1) * 2 + 1];
                    f32x4 ci;
                    ci[0] = __uint_as_float(dA << 16);
                    ci[1] = __uint_as_float(dA & 0xFFFF0000u);
                    ci[2] = __uint_as_float(dB << 16);
                    ci[3] = __uint_as_float(dB & 0xFFFF0000u);
                    s[ni] = ci;
                }
                #pragma unroll
                for (int ni = 0; ni < 4; ni++)
                    s[ni] = __builtin_amdgcn_mfma_f32_16x16x32_bf16(ka, qb[ni], s[ni], 0, 0, 0);
                #pragma unroll
                for (int ni = 0; ni < 4; ni++) {
                    float p0 = exp2_raw(s[ni][0]);
                    float p1 = exp2_raw(s[ni][1]);
                    float p2 = exp2_raw(s[ni][2]);
                    float p3 = exp2_raw(s[ni][3]);
                    Wp[mih][ni][0] = (int)pk_bf16(p0, p1);
                    Wp[mih][ni][1] = (int)pk_bf16(p2, p3);
                }
            }
            bf16x8 va0 = *(const bf16x8*)(vcur + l15 * 64 + ((ks * 4 + lg) ^ swzv) * 8);
            bf16x8 va1 = *(const bf16x8*)(vcur + (16 + l15) * 64 + ((ks * 4 + lg) ^ swzv) * 8);
            #pragma unroll
            for (int ni = 0; ni < 4; ni++) {
                i32x2 r0 = __builtin_amdgcn_permlane32_swap(Wp[0][ni][0], Wp[1][ni][0], false, false);
                i32x2 r1 = __builtin_amdgcn_permlane32_swap(Wp[0][ni][1], Wp[1][ni][1], false, false);
                int wd0, wd1, wd2, wd3;
                xswap16(r0[0], r0[1], wd0, wd2);
                xswap16(r1[0], r1[1], wd1, wd3);
                union { int wd[4]; bf16x8 v; } pu;
                pu.wd[0] = wd0; pu.wd[1] = wd1; pu.wd[2] = wd2; pu.wd[3] = wd3;
                acc[0][ni] = __builtin_amdgcn_mfma_f32_16x16x32_bf16(va0, pu.v, acc[0][ni], 0, 0, 0);
                acc[1][ni] = __builtin_amdgcn_mfma_f32_16x16x32_bf16(va1, pu.v, acc[1][ni], 0, 0, 0);
            }
        }
    }

    #pragma unroll
    for (int ni = 0; ni < 4; ni++) {
        float sum = __shfl(acc[1][ni][2], 48 + l15);
        float inv = 1.f / sum;
        int q = wv * 64 + ni * 16 + l15;
        int y = wy * 16 + (q >> 4), x = wx * 16 + (q & 15);
        u16* bp = attn_out + ((long)(y * 256 + x)) * 192 + h * 30;
        unsigned w0 = pk_bf16(acc[0][ni][0] * inv, acc[0][ni][1] * inv);
        unsigned w1 = pk_bf16(acc[0][ni][2] * inv, acc[0][ni][3] * inv);
        *(unsigned*)(bp + lg * 4)     = w0;
        *(unsigned*)(bp + lg * 4 + 2) = w1;
        unsigned w2 = pk_bf16(acc[1][ni][0] * inv, acc[1][ni][1] * inv);
        if (lg < 3) {
            unsigned w3 = pk_bf16(acc[1][ni][2] * inv, acc[1][ni][3] * inv);
            *(unsigned*)(bp + 16 + lg * 4)     = w2;
            *(unsigned*)(bp + 16 + lg * 4 + 2) = w3;
        } else {
            *(unsigned*)(bp + 28) = w2;
        }
    }
}

// ---------------------------------------------------------------------------
extern "C" void kernel_launch(void* const* d_in, const int* in_sizes, int n_in,
                              void* d_out, int out_size, void* d_ws, size_t ws_size,
                              hipStream_t stream)
{
    (void)in_sizes; (void)n_in; (void)out_size; (void)ws_size;
    const float* x      = (const float*)d_in[0];
    const int*   rpi    = (const int*)d_in[1];
    const float* n1w    = (const float*)d_in[2];
    const float* n1b    = (const float*)d_in[3];
    const float* qkv_w  = (const float*)d_in[4];
    const float* qkv_b  = (const float*)d_in[5];
    const float* rpb    = (const float*)d_in[6];
    const float* proj_w = (const float*)d_in[7];
    const float* proj_b = (const float*)d_in[8];
    const float* n2w    = (const float*)d_in[9];
    const float* n2b    = (const float*)d_in[10];
    const float* fc1_w  = (const float*)d_in[11];
    const float* fc1_b  = (const float*)d_in[12];
    const float* fc2_w  = (const float*)d_in[13];
    const float* fc2_b  = (const float*)d_in[14];
    float* out = (float*)d_out;

    char* ws = (char*)d_ws;
    size_t off = 0;
    auto alloc = [&](size_t bytes) -> void* {
        void* p = ws + off; off += (bytes + 511) & ~(size_t)511; return p;
    };
    u16*   xn     = (u16*)alloc(65536ull * 192 * 2);        // ln out; ao aliases
    u16*   q_g    = (u16*)alloc(65536ull * 192 * 2);        // [win][h][q][32]
    u16*   K_pad  = (u16*)alloc(6ull * 264 * 264 * 32 * 2); // [h][y][x][32]
    u16*   v_s    = (u16*)alloc(65536ull * 180 * 4);        // aliased with x2b
    u16*   x2b    = v_s;                                    // bf16 [t][192]
    u16*   vP     = (u16*)alloc(6ull * 32 * 264 * 272 * 2); // [h][d][y+4][x+4]
    u16*   bias5  = (u16*)alloc(6ull * 36 * 4 * 4 * 16 * 16 * 2);
    u16*   qkvT   = (u16*)alloc(640ull * 192 * 2);
    u16*   projT  = (u16*)alloc(256ull * 192 * 2);
    u16*   fc1T   = (u16*)alloc(384ull * 192 * 2);
    u16*   fc2T   = (u16*)alloc(256ull * 384 * 2);
    u16*   ao     = xn;    // ln1 zero-fills cols 180..191; attn fills 0..179
    u16*   h1     = q_g;   // fc1 out [t][384]: q_g+K_pad adjacent >= 50.3MB

    prepln_k<<<dim3(28168), dim3(256), 0, stream>>>(x, n1w, n1b, xn,
        qkv_w, proj_w, fc1_w, fc2_w, rpi, rpb,
        qkvT, projT, fc1T, fc2T, bias5, (unsigned*)K_pad, (unsigned*)vP);
    gemm_k<192, 9, 0><<<dim3(512), dim3(256), 0, stream>>>(
        xn, qkvT, qkv_b, (const float*)nullptr, q_g, K_pad, v_s);
    vtr_k<<<dim3(256, 6), dim3(256), 0, stream>>>(v_s, vP);
    attn_k<<<dim3(256, 6), dim3(256), 0, stream>>>(q_g, K_pad, vP, bias5, ao);
    gemm_k<192, 3, 1><<<dim3(512), dim3(256), 0, stream>>>(
        ao, projT, proj_b, x, x2b, nullptr, nullptr);
    lnb_k<<<dim3(16384), dim3(256), 0, stream>>>(x2b, n2w, n2b, xn);
    gemm_k<192, 6, 2><<<dim3(512), dim3(256), 0, stream>>>(
        xn, fc1T, fc1_b, (const float*)nullptr, h1, nullptr, nullptr);
    gemm_k<384, 3, 3><<<dim3(512), dim3(256), 0, stream>>>(
        h1, fc2T, fc2_b, (const float*)nullptr, out, x2b, nullptr);
}